// Round 5
// baseline (284.269 us; speedup 1.0000x reference)
//
#include <hip/hip_runtime.h>
#include <hip/hip_bf16.h>
#include <math.h>

#define B_  4
#define S_  2048
#define D_  256
#define H_  8
#define HD_ 32
#define INV_SCALE 0.17677669529663687f   // 1/sqrt(32)

typedef short  bf16x8 __attribute__((ext_vector_type(8)));
typedef float  f32x4  __attribute__((ext_vector_type(4)));
typedef unsigned short ushort_t;
typedef unsigned int   uint_t;

__device__ __forceinline__ ushort_t f2b(float f) {
    union { float f; unsigned u; } v; v.f = f;
    unsigned r = (v.u + 0x7FFFu + ((v.u >> 16) & 1u)) >> 16;
    return (ushort_t)r;
}
__device__ __forceinline__ float b2f(ushort_t s) {
    return __uint_as_float((uint_t)s << 16);
}

// ---------------- reductions ----------------
__device__ __forceinline__ float wave_sum(float v) {
#pragma unroll
    for (int o = 32; o > 0; o >>= 1) v += __shfl_down(v, o, 64);
    return v;
}
__device__ __forceinline__ float block_sum256(float v, float* scr) {
    v = wave_sum(v);
    int lane = threadIdx.x & 63, wid = threadIdx.x >> 6;
    if (lane == 0) scr[wid] = v;
    __syncthreads();
    float r = scr[0] + scr[1] + scr[2] + scr[3];
    __syncthreads();
    return r;
}

// ---------------- merged prep: adj->bits | weight cvt | layernorm ----------------
#define WQ_SZ 196608   // 768*256
#define WS_SZ 65536    // 256*256
#define NB_ADJ 65536   // (4*2048*2048)/256
#define NB_WC  2560    // (WQ_SZ+7*WS_SZ)/256
#define NB_LN  8192
__global__ __launch_bounds__(256)
void prep_kernel(const int* __restrict__ adj, uint_t* __restrict__ bits,
                 const float* __restrict__ w0, const float* __restrict__ w1,
                 const float* __restrict__ w2, const float* __restrict__ w3,
                 const float* __restrict__ w4, const float* __restrict__ w5,
                 const float* __restrict__ w6, const float* __restrict__ w7,
                 ushort_t* __restrict__ wout,
                 const float* __restrict__ x, const float* __restrict__ g,
                 const float* __restrict__ bb, ushort_t* __restrict__ xn_b) {
    __shared__ float scr[4];
    int blk = blockIdx.x, tid = threadIdx.x;
    if (blk < NB_ADJ) {
        size_t i = (size_t)blk * 256 + tid;
        unsigned long long m = __ballot(adj[i] != 0);
        int lane = tid & 63;
        size_t wbase = ((size_t)blk * 256 + (tid & ~63)) >> 5;
        if (lane == 0)  bits[wbase]     = (uint_t)m;
        if (lane == 32) bits[wbase + 1] = (uint_t)(m >> 32);
    } else if (blk < NB_ADJ + NB_WC) {
        int idx = (blk - NB_ADJ) * 256 + tid;
        const float* src; int off;
        if (idx < WQ_SZ) { src = w0; off = idx; }
        else {
            int j = idx - WQ_SZ, seg = j >> 16; off = j & (WS_SZ - 1);
            src = (seg == 0) ? w1 : (seg == 1) ? w2 : (seg == 2) ? w3 :
                  (seg == 3) ? w4 : (seg == 4) ? w5 : (seg == 5) ? w6 : w7;
        }
        wout[idx] = f2b(src[off]);
    } else {
        size_t base = (size_t)(blk - NB_ADJ - NB_WC) * D_;
        float v  = x[base + tid];
        float mu = block_sum256(v, scr) * (1.0f / D_);
        float d  = v - mu;
        float var = block_sum256(d * d, scr) * (1.0f / D_);
        float rstd = rsqrtf(var + 1e-5f);
        xn_b[base + tid] = f2b(d * rstd * g[tid] + bb[tid]);
    }
}

// ---------------- QKV GEMM: full-K LDS for A, weights streamed from L2 ----------------
// grid (12, 128): 64x64 tile, 2x2 waves. One barrier total.
__global__ __launch_bounds__(256)
void gemm_qkv(const ushort_t* __restrict__ A, const ushort_t* __restrict__ W,
              const float* __restrict__ bias, ushort_t* __restrict__ outb) {
    __shared__ ushort_t Sa[64][264];
    int tid = threadIdx.x;
    int wave = tid >> 6, lane = tid & 63, l = lane & 15, quad = lane >> 4;
    int wm = wave >> 1, wn = wave & 1;
    int m0 = blockIdx.y * 64, n0 = blockIdx.x * 64;
    {
        int row = tid >> 2, c0 = (tid & 3) * 64;
        const ushort_t* ap = A + (size_t)(m0 + row) * 256 + c0;
#pragma unroll
        for (int j = 0; j < 8; ++j)
            *(uint4*)&Sa[row][c0 + 8 * j] = ((const uint4*)ap)[j];
    }
    __syncthreads();

    bf16x8 af[2][8];
#pragma unroll
    for (int mt = 0; mt < 2; ++mt)
#pragma unroll
        for (int ks = 0; ks < 8; ++ks)
            af[mt][ks] = *(const bf16x8*)&Sa[wm * 32 + mt * 16 + l][ks * 32 + quad * 8];

    f32x4 acc[2][2];
#pragma unroll
    for (int i = 0; i < 2; ++i)
#pragma unroll
        for (int j = 0; j < 2; ++j) acc[i][j] = (f32x4){0.f, 0.f, 0.f, 0.f};

#pragma unroll
    for (int nt = 0; nt < 2; ++nt) {
        int col = n0 + wn * 32 + nt * 16 + l;
        const ushort_t* wp = W + (size_t)col * 256 + quad * 8;
        bf16x8 wfr[8];
#pragma unroll
        for (int ks = 0; ks < 8; ++ks) wfr[ks] = *(const bf16x8*)(wp + ks * 32);
#pragma unroll
        for (int ks = 0; ks < 8; ++ks) {
            acc[0][nt] = __builtin_amdgcn_mfma_f32_16x16x32_bf16(af[0][ks], wfr[ks], acc[0][nt], 0, 0, 0);
            acc[1][nt] = __builtin_amdgcn_mfma_f32_16x16x32_bf16(af[1][ks], wfr[ks], acc[1][nt], 0, 0, 0);
        }
    }

#pragma unroll
    for (int nt = 0; nt < 2; ++nt) {
        int col = n0 + wn * 32 + nt * 16 + l;
        float bv = bias[col];
        float qs = ((col % 96) < 32) ? INV_SCALE : 1.0f;
#pragma unroll
        for (int mt = 0; mt < 2; ++mt)
#pragma unroll
            for (int r = 0; r < 4; ++r) {
                int row = m0 + wm * 32 + mt * 16 + quad * 4 + r;
                outb[(size_t)row * 768 + col] = f2b((acc[mt][nt][r] + bv) * qs);
            }
    }
}

// ---------------- fully fused post-attention: fc+relu, z, r, t=r*x, p, t@ug, GRU ----------------
// grid (512): one block = 16 tokens x all 256 cols; wave w owns cols 64w..64w+63.
// y and t live only in LDS; z and p live only in registers.
__global__ __launch_bounds__(256)
void fused_gate(const ushort_t* __restrict__ attn_b, const float* __restrict__ xf,
                const ushort_t* __restrict__ wfc, const ushort_t* __restrict__ wz,
                const ushort_t* __restrict__ uz, const ushort_t* __restrict__ wr,
                const ushort_t* __restrict__ ur, const ushort_t* __restrict__ wg,
                const ushort_t* __restrict__ ug, const float* __restrict__ bfc,
                const float* __restrict__ bz, float* __restrict__ out) {
    __shared__ ushort_t Sa[16][264];
    __shared__ ushort_t Sx[16][264];
    __shared__ ushort_t Sy[16][264];
    __shared__ ushort_t St[16][264];
    int tid = threadIdx.x;
    int wave = tid >> 6, lane = tid & 63, l = lane & 15, quad = lane >> 4;
    int m0 = blockIdx.x * 16;
    int colbase = wave * 64;

    // stage attn (bf16) and x (fp32 -> bf16)
    {
        int row = tid >> 4, c0 = (tid & 15) * 16;
        const ushort_t* ap = attn_b + (size_t)(m0 + row) * 256 + c0;
        uint4 a0 = ((const uint4*)ap)[0];
        uint4 a1 = ((const uint4*)ap)[1];
        *(uint4*)&Sa[row][c0] = a0;
        *(uint4*)&Sa[row][c0 + 8] = a1;
        const float4* xp = (const float4*)(xf + (size_t)(m0 + row) * 256 + c0);
        float4 f0 = xp[0], f1 = xp[1], f2_ = xp[2], f3 = xp[3];
        union { __hip_bfloat162 h[4]; uint4 u; } p0, p1;
        p0.h[0] = __float22bfloat162_rn(make_float2(f0.x, f0.y));
        p0.h[1] = __float22bfloat162_rn(make_float2(f0.z, f0.w));
        p0.h[2] = __float22bfloat162_rn(make_float2(f1.x, f1.y));
        p0.h[3] = __float22bfloat162_rn(make_float2(f1.z, f1.w));
        p1.h[0] = __float22bfloat162_rn(make_float2(f2_.x, f2_.y));
        p1.h[1] = __float22bfloat162_rn(make_float2(f2_.z, f2_.w));
        p1.h[2] = __float22bfloat162_rn(make_float2(f3.x, f3.y));
        p1.h[3] = __float22bfloat162_rn(make_float2(f3.z, f3.w));
        *(uint4*)&Sx[row][c0]     = p0.u;
        *(uint4*)&Sx[row][c0 + 8] = p1.u;
    }
    __syncthreads();

    // ---- GEMM1: y = relu(attn @ wfc^T + bfc) -> Sy ----
    {
        bf16x8 af[8];
#pragma unroll
        for (int ks = 0; ks < 8; ++ks)
            af[ks] = *(const bf16x8*)&Sa[l][ks * 32 + quad * 8];
        f32x4 ya[4];
#pragma unroll
        for (int nt = 0; nt < 4; ++nt) ya[nt] = (f32x4){0.f, 0.f, 0.f, 0.f};
#pragma unroll
        for (int nt = 0; nt < 4; ++nt) {
            const ushort_t* wp = wfc + (size_t)(colbase + nt * 16 + l) * 256 + quad * 8;
            bf16x8 wfr[8];
#pragma unroll
            for (int ks = 0; ks < 8; ++ks) wfr[ks] = *(const bf16x8*)(wp + ks * 32);
#pragma unroll
            for (int ks = 0; ks < 8; ++ks)
                ya[nt] = __builtin_amdgcn_mfma_f32_16x16x32_bf16(af[ks], wfr[ks], ya[nt], 0, 0, 0);
        }
#pragma unroll
        for (int nt = 0; nt < 4; ++nt) {
            int col = colbase + nt * 16 + l;
            float bv = bfc[col];
#pragma unroll
            for (int r = 0; r < 4; ++r)
                Sy[quad * 4 + r][col] = f2b(fmaxf(ya[nt][r] + bv, 0.0f));
        }
    }
    __syncthreads();

    // ---- gate GEMMs: az = y@wz + x@uz ; ar = y@wr + x@ur ; ag = y@wg ----
    f32x4 az[4], ar[4], ag[4];
#pragma unroll
    for (int nt = 0; nt < 4; ++nt) {
        az[nt] = (f32x4){0.f, 0.f, 0.f, 0.f};
        ar[nt] = (f32x4){0.f, 0.f, 0.f, 0.f};
        ag[nt] = (f32x4){0.f, 0.f, 0.f, 0.f};
    }
#pragma unroll
    for (int nt = 0; nt < 4; ++nt) {
        size_t wo = (size_t)(colbase + nt * 16 + l) * 256 + quad * 8;
#pragma unroll
        for (int ks = 0; ks < 8; ++ks) {
            bf16x8 fy = *(const bf16x8*)&Sy[l][ks * 32 + quad * 8];
            bf16x8 fx = *(const bf16x8*)&Sx[l][ks * 32 + quad * 8];
            bf16x8 fz  = *(const bf16x8*)(wz + wo + ks * 32);
            bf16x8 fuz = *(const bf16x8*)(uz + wo + ks * 32);
            bf16x8 fr  = *(const bf16x8*)(wr + wo + ks * 32);
            bf16x8 fur = *(const bf16x8*)(ur + wo + ks * 32);
            bf16x8 fg  = *(const bf16x8*)(wg + wo + ks * 32);
            az[nt] = __builtin_amdgcn_mfma_f32_16x16x32_bf16(fy, fz,  az[nt], 0, 0, 0);
            az[nt] = __builtin_amdgcn_mfma_f32_16x16x32_bf16(fx, fuz, az[nt], 0, 0, 0);
            ar[nt] = __builtin_amdgcn_mfma_f32_16x16x32_bf16(fy, fr,  ar[nt], 0, 0, 0);
            ar[nt] = __builtin_amdgcn_mfma_f32_16x16x32_bf16(fx, fur, ar[nt], 0, 0, 0);
            ag[nt] = __builtin_amdgcn_mfma_f32_16x16x32_bf16(fy, fg,  ag[nt], 0, 0, 0);
        }
    }
    // epilogue: z -> az (registers), t = sigmoid(r)*x -> St
#pragma unroll
    for (int nt = 0; nt < 4; ++nt) {
        int col = colbase + nt * 16 + l;
        float bzv = bz[col];
#pragma unroll
        for (int r = 0; r < 4; ++r) {
            int row = quad * 4 + r;
            az[nt][r] = 1.0f / (1.0f + __expf(-(az[nt][r] + bzv)));
            float rr  = 1.0f / (1.0f + __expf(-ar[nt][r]));
            St[row][col] = f2b(rr * b2f(Sx[row][col]));
        }
    }
    __syncthreads();

    // ---- GEMM3: fcc = t @ ug^T ; out = (1-z)*x + z*tanh(p + fcc) ----
    f32x4 fcc[4];
#pragma unroll
    for (int nt = 0; nt < 4; ++nt) fcc[nt] = (f32x4){0.f, 0.f, 0.f, 0.f};
#pragma unroll
    for (int nt = 0; nt < 4; ++nt) {
        size_t wo = (size_t)(colbase + nt * 16 + l) * 256 + quad * 8;
#pragma unroll
        for (int ks = 0; ks < 8; ++ks) {
            bf16x8 ft = *(const bf16x8*)&St[l][ks * 32 + quad * 8];
            bf16x8 fu = *(const bf16x8*)(ug + wo + ks * 32);
            fcc[nt] = __builtin_amdgcn_mfma_f32_16x16x32_bf16(ft, fu, fcc[nt], 0, 0, 0);
        }
    }
#pragma unroll
    for (int nt = 0; nt < 4; ++nt) {
        int col = colbase + nt * 16 + l;
#pragma unroll
        for (int r = 0; r < 4; ++r) {
            int row = quad * 4 + r;
            float v = ag[nt][r] + fcc[nt][r];
            float e = __expf(2.0f * v);
            float h = 1.0f - 2.0f / (e + 1.0f);        // tanh(v), saturates correctly
            float zz = az[nt][r];
            size_t idx = (size_t)(m0 + row) * 256 + col;
            out[idx] = (1.0f - zz) * xf[idx] + zz * h;
        }
    }
}

// ---------------- MFMA flash attention (S^T layout) — unchanged from R3 ----------------
__global__ __launch_bounds__(256)
void attn_kernel(const ushort_t* __restrict__ qkvb, const uint_t* __restrict__ abits,
                 ushort_t* __restrict__ attn_b) {
    __shared__ ushort_t Ks[64][40];   // [key][d]
    __shared__ ushort_t Vt[32][72];   // [d][key], col-block ^= (d>>3)&3
    __shared__ ushort_t Ps[64][72];   // [q][key], wave-private 16-row bands
    __shared__ uint_t  ab_sh[64][2];

    int tid = threadIdx.x;
    int wave = tid >> 6, lane = tid & 63, l = lane & 15, quad = lane >> 4;
    int q0 = blockIdx.x * 64;
    int n  = blockIdx.y;
    int b = n >> 3, h = n & 7;
    int bp = n & 3, hp = n >> 2;

    const ushort_t* base = qkvb + (size_t)b * S_ * 768 + h * 96;
    int myq = wave * 16 + l;

    bf16x8 qf = *(const bf16x8*)(base + (size_t)(q0 + myq) * 768 + quad * 8);

    f32x4 oacc[2];
    oacc[0] = (f32x4){0.f, 0.f, 0.f, 0.f};
    oacc[1] = (f32x4){0.f, 0.f, 0.f, 0.f};
    float lsum = 0.0f;

    int skey = tid >> 2, spart = tid & 3;
    int sblk = skey >> 3, scol = skey & 7;

    uint4 kv = *(const uint4*)(base + (size_t)skey * 768 + 32 + spart * 8);
    uint4 vv = *(const uint4*)(base + (size_t)skey * 768 + 64 + spart * 8);
    uint_t aw = 0;
    if (tid < 128)
        aw = abits[((size_t)b * S_ + q0 + (tid >> 1)) * 64 + (tid & 1)];

    for (int k0 = 0; k0 < S_; k0 += 64) {
        uint4 kc = kv, vc = vv; uint_t ac = aw;
        if (k0 + 64 < S_) {
            kv = *(const uint4*)(base + (size_t)(k0 + 64 + skey) * 768 + 32 + spart * 8);
            vv = *(const uint4*)(base + (size_t)(k0 + 64 + skey) * 768 + 64 + spart * 8);
            if (tid < 128)
                aw = abits[((size_t)b * S_ + q0 + (tid >> 1)) * 64 + ((k0 + 64) >> 5) + (tid & 1)];
        }
        __syncthreads();
        *(uint4*)&Ks[skey][spart * 8] = kc;
        {
            const ushort_t* vs = (const ushort_t*)&vc;
            int cb = ((sblk ^ spart) << 3) | scol;
#pragma unroll
            for (int i = 0; i < 8; ++i) Vt[spart * 8 + i][cb] = vs[i];
        }
        if (tid < 128) ab_sh[tid >> 1][tid & 1] = ac;
        __syncthreads();

        uint_t aw0 = ab_sh[myq][0], aw1 = ab_sh[myq][1];

#pragma unroll
        for (int t4 = 0; t4 < 4; ++t4) {
            bf16x8 kf = *(const bf16x8*)&Ks[t4 * 16 + l][quad * 8];
            f32x4 z = (f32x4){0.f, 0.f, 0.f, 0.f};
            f32x4 sc = __builtin_amdgcn_mfma_f32_16x16x32_bf16(kf, qf, z, 0, 0, 0);
            uint_t w = (t4 & 2) ? aw1 : aw0;
            uint_t wq = w >> ((t4 & 1) * 16 + quad * 4);
            float p[4];
#pragma unroll
            for (int r = 0; r < 4; ++r) {
                uint_t mneg = 0u - ((wq >> r) & 1u);
                float e = __expf(sc[r]);
                p[r] = __uint_as_float(__float_as_uint(e) & mneg);
                lsum += p[r];
            }
            union { __hip_bfloat162 b2[2]; uint2 u2; } pk;
            pk.b2[0] = __float22bfloat162_rn(make_float2(p[0], p[1]));
            pk.b2[1] = __float22bfloat162_rn(make_float2(p[2], p[3]));
            *(uint2*)&Ps[myq][t4 * 16 + quad * 4] = pk.u2;
        }

#pragma unroll
        for (int ks = 0; ks < 2; ++ks) {
            bf16x8 pf = *(const bf16x8*)&Ps[wave * 16 + l][ks * 32 + quad * 8];
#pragma unroll
            for (int mt = 0; mt < 2; ++mt) {
                int dblk = (mt * 2 + (l >> 3)) & 3;
                bf16x8 vf = *(const bf16x8*)&Vt[mt * 16 + l][(((ks * 4 + quad) ^ dblk) & 7) * 8];
                oacc[mt] = __builtin_amdgcn_mfma_f32_16x16x32_bf16(vf, pf, oacc[mt], 0, 0, 0);
            }
        }
    }

    lsum += __shfl_xor(lsum, 16, 64);
    lsum += __shfl_xor(lsum, 32, 64);
    float linv = 1.0f / lsum;

    size_t orow = ((size_t)(bp * S_ + q0 + myq)) * D_ + hp * HD_;
#pragma unroll
    for (int mt = 0; mt < 2; ++mt)
#pragma unroll
        for (int r = 0; r < 4; ++r)
            attn_b[orow + mt * 16 + quad * 4 + r] = f2b(oacc[mt][r] * linv);
}

// ---------------- launch ----------------
extern "C" void kernel_launch(void* const* d_in, const int* in_sizes, int n_in,
                              void* d_out, int out_size, void* d_ws, size_t ws_size,
                              hipStream_t stream) {
    const float* x     = (const float*)d_in[0];
    const int*   adj   = (const int*)d_in[1];
    const float* w_qkv = (const float*)d_in[2];
    const float* b_qkv = (const float*)d_in[3];
    const float* ln_g  = (const float*)d_in[4];
    const float* ln_b  = (const float*)d_in[5];
    const float* w_fc  = (const float*)d_in[6];
    const float* b_fc  = (const float*)d_in[7];
    const float* w_z   = (const float*)d_in[8];
    const float* b_z   = (const float*)d_in[9];
    const float* u_z   = (const float*)d_in[10];
    const float* w_r   = (const float*)d_in[11];
    const float* u_r   = (const float*)d_in[12];
    const float* w_g   = (const float*)d_in[13];
    const float* u_g   = (const float*)d_in[14];
    float* out = (float*)d_out;

    const size_t TOK  = (size_t)B_ * S_;       // 8192
    const size_t TOKD = TOK * D_;              // 2,097,152
    ushort_t* xn_b   = (ushort_t*)d_ws;
    ushort_t* qkv_b  = xn_b + TOKD;            // TOK*768
    ushort_t* attn_b = qkv_b + TOK * 768;
    ushort_t* wb     = attn_b + TOKD;          // 655,360 elems
    uint_t*   bits   = (uint_t*)(wb + WQ_SZ + 7 * WS_SZ);

    ushort_t* wq_b  = wb;
    ushort_t* wfc_b = wb + WQ_SZ;
    ushort_t* wz_b  = wfc_b + WS_SZ;
    ushort_t* uz_b  = wz_b + WS_SZ;
    ushort_t* wr_b  = uz_b + WS_SZ;
    ushort_t* ur_b  = wr_b + WS_SZ;
    ushort_t* wg_b  = ur_b + WS_SZ;
    ushort_t* ug_b  = wg_b + WS_SZ;

    prep_kernel<<<NB_ADJ + NB_WC + NB_LN, 256, 0, stream>>>(
        adj, bits, w_qkv, w_fc, w_z, u_z, w_r, u_r, w_g, u_g, wb,
        x, ln_g, ln_b, xn_b);

    gemm_qkv<<<dim3(12, 128), 256, 0, stream>>>(xn_b, wq_b, b_qkv, qkv_b);

    attn_kernel<<<dim3(S_ / 64, B_ * H_), 256, 0, stream>>>(qkv_b, bits, attn_b);

    fused_gate<<<512, 256, 0, stream>>>(
        attn_b, x, wfc_b, wz_b, uz_b, wr_b, ur_b, wg_b, ug_b, b_fc, b_z, out);
}

// Round 6
// 247.081 us; speedup vs baseline: 1.1505x; 1.1505x over previous
//
#include <hip/hip_runtime.h>
#include <hip/hip_bf16.h>
#include <math.h>

#define B_  4
#define S_  2048
#define D_  256
#define H_  8
#define HD_ 32
#define INV_SCALE 0.17677669529663687f   // 1/sqrt(32)

typedef short  bf16x8 __attribute__((ext_vector_type(8)));
typedef float  f32x4  __attribute__((ext_vector_type(4)));
typedef unsigned short ushort_t;
typedef unsigned int   uint_t;

__device__ __forceinline__ ushort_t f2b(float f) {
    union { float f; unsigned u; } v; v.f = f;
    unsigned r = (v.u + 0x7FFFu + ((v.u >> 16) & 1u)) >> 16;
    return (ushort_t)r;
}
__device__ __forceinline__ float b2f(ushort_t s) {
    return __uint_as_float((uint_t)s << 16);
}

// ---------------- reductions ----------------
__device__ __forceinline__ float wave_sum(float v) {
#pragma unroll
    for (int o = 32; o > 0; o >>= 1) v += __shfl_down(v, o, 64);
    return v;
}
__device__ __forceinline__ float block_sum256(float v, float* scr) {
    v = wave_sum(v);
    int lane = threadIdx.x & 63, wid = threadIdx.x >> 6;
    if (lane == 0) scr[wid] = v;
    __syncthreads();
    float r = scr[0] + scr[1] + scr[2] + scr[3];
    __syncthreads();
    return r;
}

// ---------------- merged prep: adj->bits | weight cvt+frag-reorder | layernorm ----------------
// Weights are emitted in MFMA fragment-linear order:
//   off = (((colTile*8 + ks)*4 + quad)*16 + l)*8 + j
//   value = W[colTile*16 + l][ks*32 + quad*8 + j]
// so a wave (lane = quad*16+l) fragment load is one contiguous 1 KB block.
#define WQ_SZ 196608   // 768*256
#define WS_SZ 65536    // 256*256
#define NB_ADJ 65536   // (4*2048*2048)/256
#define NB_WC  2560    // (WQ_SZ+7*WS_SZ)/256
#define NB_LN  8192
__global__ __launch_bounds__(256)
void prep_kernel(const int* __restrict__ adj, uint_t* __restrict__ bits,
                 const float* __restrict__ w0, const float* __restrict__ w1,
                 const float* __restrict__ w2, const float* __restrict__ w3,
                 const float* __restrict__ w4, const float* __restrict__ w5,
                 const float* __restrict__ w6, const float* __restrict__ w7,
                 ushort_t* __restrict__ wout,
                 const float* __restrict__ x, const float* __restrict__ g,
                 const float* __restrict__ bb, ushort_t* __restrict__ xn_b) {
    __shared__ float scr[4];
    int blk = blockIdx.x, tid = threadIdx.x;
    if (blk < NB_ADJ) {
        size_t i = (size_t)blk * 256 + tid;
        unsigned long long m = __ballot(adj[i] != 0);
        int lane = tid & 63;
        size_t wbase = ((size_t)blk * 256 + (tid & ~63)) >> 5;
        if (lane == 0)  bits[wbase]     = (uint_t)m;
        if (lane == 32) bits[wbase + 1] = (uint_t)(m >> 32);
    } else if (blk < NB_ADJ + NB_WC) {
        int idx = (blk - NB_ADJ) * 256 + tid;
        const float* src; int o;
        if (idx < WQ_SZ) { src = w0; o = idx; }
        else {
            int j = idx - WQ_SZ, seg = j >> 16; o = j & (WS_SZ - 1);
            src = (seg == 0) ? w1 : (seg == 1) ? w2 : (seg == 2) ? w3 :
                  (seg == 3) ? w4 : (seg == 4) ? w5 : (seg == 5) ? w6 : w7;
        }
        int j  = o & 7;
        int l  = (o >> 3) & 15;
        int qd = (o >> 7) & 3;
        int ks = (o >> 9) & 7;
        int ct = o >> 12;
        wout[idx] = f2b(src[(ct * 16 + l) * 256 + ks * 32 + qd * 8 + j]);
    } else {
        size_t base = (size_t)(blk - NB_ADJ - NB_WC) * D_;
        float v  = x[base + tid];
        float mu = block_sum256(v, scr) * (1.0f / D_);
        float d  = v - mu;
        float var = block_sum256(d * d, scr) * (1.0f / D_);
        float rstd = rsqrtf(var + 1e-5f);
        xn_b[base + tid] = f2b(d * rstd * g[tid] + bb[tid]);
    }
}

// ---------------- QKV GEMM: full-K LDS A, frag-ordered weights, coalesced stores ----------------
// grid (12, 128): 64x64 tile, 2x2 waves.
__global__ __launch_bounds__(256)
void gemm_qkv(const ushort_t* __restrict__ A, const ushort_t* __restrict__ Wf,
              const float* __restrict__ bias, ushort_t* __restrict__ outb) {
    __shared__ ushort_t Sa[64][264];
    int tid = threadIdx.x;
    int wave = tid >> 6, lane = tid & 63, l = lane & 15, quad = lane >> 4;
    int wm = wave >> 1, wn = wave & 1;
    int m0 = blockIdx.y * 64, n0 = blockIdx.x * 64;
    {
        int row = tid >> 2, c0 = (tid & 3) * 64;
        const ushort_t* ap = A + (size_t)(m0 + row) * 256 + c0;
#pragma unroll
        for (int j = 0; j < 8; ++j)
            *(uint4*)&Sa[row][c0 + 8 * j] = ((const uint4*)ap)[j];
    }
    __syncthreads();

    bf16x8 af[2][8];
#pragma unroll
    for (int mt = 0; mt < 2; ++mt)
#pragma unroll
        for (int ks = 0; ks < 8; ++ks)
            af[mt][ks] = *(const bf16x8*)&Sa[wm * 32 + mt * 16 + l][ks * 32 + quad * 8];

    f32x4 acc[2][2];
#pragma unroll
    for (int i = 0; i < 2; ++i)
#pragma unroll
        for (int j = 0; j < 2; ++j) acc[i][j] = (f32x4){0.f, 0.f, 0.f, 0.f};

#pragma unroll
    for (int nt = 0; nt < 2; ++nt) {
        int ct = (n0 >> 4) + wn * 2 + nt;
        bf16x8 wfr[8];
#pragma unroll
        for (int ks = 0; ks < 8; ++ks)
            wfr[ks] = *(const bf16x8*)(Wf + (((size_t)ct * 8 + ks) * 64 + lane) * 8);
#pragma unroll
        for (int ks = 0; ks < 8; ++ks) {
            acc[0][nt] = __builtin_amdgcn_mfma_f32_16x16x32_bf16(af[0][ks], wfr[ks], acc[0][nt], 0, 0, 0);
            acc[1][nt] = __builtin_amdgcn_mfma_f32_16x16x32_bf16(af[1][ks], wfr[ks], acc[1][nt], 0, 0, 0);
        }
    }

    // coalesced epilogue: stage 64x64 bf16 tile in LDS, store uint4
    __syncthreads();
    ushort_t* So = &Sa[0][0];    // stride 72, 64*72 <= 64*264
#pragma unroll
    for (int nt = 0; nt < 2; ++nt) {
        int col = wn * 32 + nt * 16 + l;
        int gcol = n0 + col;
        float bv = bias[gcol];
        float qs = ((gcol % 96) < 32) ? INV_SCALE : 1.0f;
#pragma unroll
        for (int mt = 0; mt < 2; ++mt)
#pragma unroll
            for (int r = 0; r < 4; ++r) {
                int row = wm * 32 + mt * 16 + quad * 4 + r;
                So[row * 72 + col] = f2b((acc[mt][nt][r] + bv) * qs);
            }
    }
    __syncthreads();
    {
        int row = tid >> 2, seg = tid & 3;
        uint4 v0 = *(uint4*)&So[row * 72 + seg * 16];
        uint4 v1 = *(uint4*)&So[row * 72 + seg * 16 + 8];
        ushort_t* op = outb + (size_t)(m0 + row) * 768 + n0 + seg * 16;
        ((uint4*)op)[0] = v0;
        ((uint4*)op)[1] = v1;
    }
}

// ---------------- fully fused post-attention (frag-ordered weights) ----------------
// grid (512): one block = 16 tokens x 256 cols; wave w owns cols 64w..64w+63.
__global__ __launch_bounds__(256)
void fused_gate(const ushort_t* __restrict__ attn_b, const float* __restrict__ xf,
                const ushort_t* __restrict__ wfc, const ushort_t* __restrict__ wz,
                const ushort_t* __restrict__ uz, const ushort_t* __restrict__ wr,
                const ushort_t* __restrict__ ur, const ushort_t* __restrict__ wg,
                const ushort_t* __restrict__ ug, const float* __restrict__ bfc,
                const float* __restrict__ bz, float* __restrict__ out) {
    __shared__ ushort_t Sa[16][264];
    __shared__ ushort_t Sx[16][264];
    __shared__ ushort_t Sy[16][264];
    __shared__ ushort_t St[16][264];
    int tid = threadIdx.x;
    int wave = tid >> 6, lane = tid & 63, l = lane & 15, quad = lane >> 4;
    int m0 = blockIdx.x * 16;
    int colbase = wave * 64;

    {
        int row = tid >> 4, c0 = (tid & 15) * 16;
        const ushort_t* ap = attn_b + (size_t)(m0 + row) * 256 + c0;
        uint4 a0 = ((const uint4*)ap)[0];
        uint4 a1 = ((const uint4*)ap)[1];
        *(uint4*)&Sa[row][c0] = a0;
        *(uint4*)&Sa[row][c0 + 8] = a1;
        const float4* xp = (const float4*)(xf + (size_t)(m0 + row) * 256 + c0);
        float4 f0 = xp[0], f1 = xp[1], f2_ = xp[2], f3 = xp[3];
        union { __hip_bfloat162 h[4]; uint4 u; } p0, p1;
        p0.h[0] = __float22bfloat162_rn(make_float2(f0.x, f0.y));
        p0.h[1] = __float22bfloat162_rn(make_float2(f0.z, f0.w));
        p0.h[2] = __float22bfloat162_rn(make_float2(f1.x, f1.y));
        p0.h[3] = __float22bfloat162_rn(make_float2(f1.z, f1.w));
        p1.h[0] = __float22bfloat162_rn(make_float2(f2_.x, f2_.y));
        p1.h[1] = __float22bfloat162_rn(make_float2(f2_.z, f2_.w));
        p1.h[2] = __float22bfloat162_rn(make_float2(f3.x, f3.y));
        p1.h[3] = __float22bfloat162_rn(make_float2(f3.z, f3.w));
        *(uint4*)&Sx[row][c0]     = p0.u;
        *(uint4*)&Sx[row][c0 + 8] = p1.u;
    }
    __syncthreads();

    // ---- GEMM1: y = relu(attn @ wfc^T + bfc) -> Sy ----
    {
        bf16x8 af[8];
#pragma unroll
        for (int ks = 0; ks < 8; ++ks)
            af[ks] = *(const bf16x8*)&Sa[l][ks * 32 + quad * 8];
        f32x4 ya[4];
#pragma unroll
        for (int nt = 0; nt < 4; ++nt) ya[nt] = (f32x4){0.f, 0.f, 0.f, 0.f};
#pragma unroll
        for (int nt = 0; nt < 4; ++nt) {
            size_t fb = ((size_t)(wave * 4 + nt) * 8) * 512 + lane * 8;
#pragma unroll
            for (int ks = 0; ks < 8; ++ks) {
                bf16x8 wfr = *(const bf16x8*)(wfc + fb + ks * 512);
                ya[nt] = __builtin_amdgcn_mfma_f32_16x16x32_bf16(af[ks], wfr, ya[nt], 0, 0, 0);
            }
        }
#pragma unroll
        for (int nt = 0; nt < 4; ++nt) {
            int col = colbase + nt * 16 + l;
            float bv = bfc[col];
#pragma unroll
            for (int r = 0; r < 4; ++r)
                Sy[quad * 4 + r][col] = f2b(fmaxf(ya[nt][r] + bv, 0.0f));
        }
    }
    __syncthreads();

    // ---- gate GEMMs ----
    f32x4 az[4], ar[4], ag[4];
#pragma unroll
    for (int nt = 0; nt < 4; ++nt) {
        az[nt] = (f32x4){0.f, 0.f, 0.f, 0.f};
        ar[nt] = (f32x4){0.f, 0.f, 0.f, 0.f};
        ag[nt] = (f32x4){0.f, 0.f, 0.f, 0.f};
    }
#pragma unroll
    for (int nt = 0; nt < 4; ++nt) {
        size_t fb = ((size_t)(wave * 4 + nt) * 8) * 512 + lane * 8;
#pragma unroll
        for (int ks = 0; ks < 8; ++ks) {
            bf16x8 fy = *(const bf16x8*)&Sy[l][ks * 32 + quad * 8];
            bf16x8 fx = *(const bf16x8*)&Sx[l][ks * 32 + quad * 8];
            bf16x8 fz  = *(const bf16x8*)(wz + fb + ks * 512);
            bf16x8 fuz = *(const bf16x8*)(uz + fb + ks * 512);
            bf16x8 fr  = *(const bf16x8*)(wr + fb + ks * 512);
            bf16x8 fur = *(const bf16x8*)(ur + fb + ks * 512);
            bf16x8 fg  = *(const bf16x8*)(wg + fb + ks * 512);
            az[nt] = __builtin_amdgcn_mfma_f32_16x16x32_bf16(fy, fz,  az[nt], 0, 0, 0);
            az[nt] = __builtin_amdgcn_mfma_f32_16x16x32_bf16(fx, fuz, az[nt], 0, 0, 0);
            ar[nt] = __builtin_amdgcn_mfma_f32_16x16x32_bf16(fy, fr,  ar[nt], 0, 0, 0);
            ar[nt] = __builtin_amdgcn_mfma_f32_16x16x32_bf16(fx, fur, ar[nt], 0, 0, 0);
            ag[nt] = __builtin_amdgcn_mfma_f32_16x16x32_bf16(fy, fg,  ag[nt], 0, 0, 0);
        }
    }
#pragma unroll
    for (int nt = 0; nt < 4; ++nt) {
        int col = colbase + nt * 16 + l;
        float bzv = bz[col];
#pragma unroll
        for (int r = 0; r < 4; ++r) {
            int row = quad * 4 + r;
            az[nt][r] = 1.0f / (1.0f + __expf(-(az[nt][r] + bzv)));
            float rr  = 1.0f / (1.0f + __expf(-ar[nt][r]));
            St[row][col] = f2b(rr * b2f(Sx[row][col]));
        }
    }
    __syncthreads();

    // ---- GEMM3 + GRU combine ----
    f32x4 fcc[4];
#pragma unroll
    for (int nt = 0; nt < 4; ++nt) fcc[nt] = (f32x4){0.f, 0.f, 0.f, 0.f};
#pragma unroll
    for (int nt = 0; nt < 4; ++nt) {
        size_t fb = ((size_t)(wave * 4 + nt) * 8) * 512 + lane * 8;
#pragma unroll
        for (int ks = 0; ks < 8; ++ks) {
            bf16x8 ft = *(const bf16x8*)&St[l][ks * 32 + quad * 8];
            bf16x8 fu = *(const bf16x8*)(ug + fb + ks * 512);
            fcc[nt] = __builtin_amdgcn_mfma_f32_16x16x32_bf16(ft, fu, fcc[nt], 0, 0, 0);
        }
    }
#pragma unroll
    for (int nt = 0; nt < 4; ++nt) {
        int col = colbase + nt * 16 + l;
#pragma unroll
        for (int r = 0; r < 4; ++r) {
            int row = quad * 4 + r;
            float v = ag[nt][r] + fcc[nt][r];
            float e = __expf(2.0f * v);
            float h = 1.0f - 2.0f / (e + 1.0f);
            float zz = az[nt][r];
            size_t idx = (size_t)(m0 + row) * 256 + col;
            out[idx] = (1.0f - zz) * xf[idx] + zz * h;
        }
    }
}

// ---------------- MFMA flash attention (S^T layout, swizzled LDS, coalesced out) ----------------
__global__ __launch_bounds__(256)
void attn_kernel(const ushort_t* __restrict__ qkvb, const uint_t* __restrict__ abits,
                 ushort_t* __restrict__ attn_b) {
    __shared__ ushort_t Ks[64][40];   // [key][d ^ ((key>>3&1)<<3)]
    __shared__ ushort_t Vt[32][72];   // [d][key ^ ((d>>3)<<4)]  (injective col swizzle)
    __shared__ ushort_t Ps[64][72];   // [q][key], wave-private 16-row bands
    __shared__ uint_t  ab_sh[64][2];

    int tid = threadIdx.x;
    int wave = tid >> 6, lane = tid & 63, l = lane & 15, quad = lane >> 4;
    int q0 = blockIdx.x * 64;
    int n  = blockIdx.y;
    int b = n >> 3, h = n & 7;
    int bp = n & 3, hp = n >> 2;

    const ushort_t* base = qkvb + (size_t)b * S_ * 768 + h * 96;
    int myq = wave * 16 + l;

    bf16x8 qf = *(const bf16x8*)(base + (size_t)(q0 + myq) * 768 + quad * 8);

    f32x4 oacc[2];
    oacc[0] = (f32x4){0.f, 0.f, 0.f, 0.f};
    oacc[1] = (f32x4){0.f, 0.f, 0.f, 0.f};
    float lsum = 0.0f;

    int skey = tid >> 2, spart = tid & 3;
    int kcol = (spart * 8) ^ (((skey >> 3) & 1) << 3);
    int vcol = skey ^ (spart << 4);

    uint4 kv = *(const uint4*)(base + (size_t)skey * 768 + 32 + spart * 8);
    uint4 vv = *(const uint4*)(base + (size_t)skey * 768 + 64 + spart * 8);
    uint_t aw = 0;
    if (tid < 128)
        aw = abits[((size_t)b * S_ + q0 + (tid >> 1)) * 64 + (tid & 1)];

    for (int k0 = 0; k0 < S_; k0 += 64) {
        uint4 kc = kv, vc = vv; uint_t ac = aw;
        if (k0 + 64 < S_) {
            kv = *(const uint4*)(base + (size_t)(k0 + 64 + skey) * 768 + 32 + spart * 8);
            vv = *(const uint4*)(base + (size_t)(k0 + 64 + skey) * 768 + 64 + spart * 8);
            if (tid < 128)
                aw = abits[((size_t)b * S_ + q0 + (tid >> 1)) * 64 + ((k0 + 64) >> 5) + (tid & 1)];
        }
        __syncthreads();
        *(uint4*)&Ks[skey][kcol] = kc;
        {
            const ushort_t* vs = (const ushort_t*)&vc;
#pragma unroll
            for (int i = 0; i < 8; ++i) Vt[spart * 8 + i][vcol] = vs[i];
        }
        if (tid < 128) ab_sh[tid >> 1][tid & 1] = ac;
        __syncthreads();

        uint_t aw0 = ab_sh[myq][0], aw1 = ab_sh[myq][1];

#pragma unroll
        for (int t4 = 0; t4 < 4; ++t4) {
            bf16x8 kf = *(const bf16x8*)&Ks[t4 * 16 + l][(quad * 8) ^ ((l >> 3) << 3)];
            f32x4 z = (f32x4){0.f, 0.f, 0.f, 0.f};
            f32x4 sc = __builtin_amdgcn_mfma_f32_16x16x32_bf16(kf, qf, z, 0, 0, 0);
            uint_t w = (t4 & 2) ? aw1 : aw0;
            uint_t wq = w >> ((t4 & 1) * 16 + quad * 4);
            float p[4];
#pragma unroll
            for (int r = 0; r < 4; ++r) {
                uint_t mneg = 0u - ((wq >> r) & 1u);
                float e = __expf(sc[r]);
                p[r] = __uint_as_float(__float_as_uint(e) & mneg);
                lsum += p[r];
            }
            union { __hip_bfloat162 b2[2]; uint2 u2; } pk;
            pk.b2[0] = __float22bfloat162_rn(make_float2(p[0], p[1]));
            pk.b2[1] = __float22bfloat162_rn(make_float2(p[2], p[3]));
            *(uint2*)&Ps[myq][t4 * 16 + quad * 4] = pk.u2;
        }

#pragma unroll
        for (int ks = 0; ks < 2; ++ks) {
            bf16x8 pf = *(const bf16x8*)&Ps[wave * 16 + l][ks * 32 + quad * 8];
#pragma unroll
            for (int mt = 0; mt < 2; ++mt) {
                int vc2 = (ks * 32 + quad * 8) ^ ((mt * 2 + (l >> 3)) << 4);
                bf16x8 vf = *(const bf16x8*)&Vt[mt * 16 + l][vc2];
                oacc[mt] = __builtin_amdgcn_mfma_f32_16x16x32_bf16(vf, pf, oacc[mt], 0, 0, 0);
            }
        }
    }

    lsum += __shfl_xor(lsum, 16, 64);
    lsum += __shfl_xor(lsum, 32, 64);
    float linv = 1.0f / lsum;

    // coalesced epilogue: stage 64x32 tile in LDS (reuse Ks), uint4 stores
    __syncthreads();
    ushort_t* Ost = &Ks[0][0];   // stride 40
#pragma unroll
    for (int mt = 0; mt < 2; ++mt)
#pragma unroll
        for (int r = 0; r < 4; ++r)
            Ost[myq * 40 + mt * 16 + quad * 4 + r] = f2b(oacc[mt][r] * linv);
    __syncthreads();
    {
        int q = tid >> 2, part = tid & 3;
        uint4 v = *(uint4*)&Ost[q * 40 + part * 8];
        *(uint4*)&attn_b[((size_t)(bp * S_ + q0 + q)) * 256 + hp * 32 + part * 8] = v;
    }
}

// ---------------- launch ----------------
extern "C" void kernel_launch(void* const* d_in, const int* in_sizes, int n_in,
                              void* d_out, int out_size, void* d_ws, size_t ws_size,
                              hipStream_t stream) {
    const float* x     = (const float*)d_in[0];
    const int*   adj   = (const int*)d_in[1];
    const float* w_qkv = (const float*)d_in[2];
    const float* b_qkv = (const float*)d_in[3];
    const float* ln_g  = (const float*)d_in[4];
    const float* ln_b  = (const float*)d_in[5];
    const float* w_fc  = (const float*)d_in[6];
    const float* b_fc  = (const float*)d_in[7];
    const float* w_z   = (const float*)d_in[8];
    const float* b_z   = (const float*)d_in[9];
    const float* u_z   = (const float*)d_in[10];
    const float* w_r   = (const float*)d_in[11];
    const float* u_r   = (const float*)d_in[12];
    const float* w_g   = (const float*)d_in[13];
    const float* u_g   = (const float*)d_in[14];
    float* out = (float*)d_out;

    const size_t TOK  = (size_t)B_ * S_;       // 8192
    const size_t TOKD = TOK * D_;              // 2,097,152
    ushort_t* xn_b   = (ushort_t*)d_ws;
    ushort_t* qkv_b  = xn_b + TOKD;            // TOK*768
    ushort_t* attn_b = qkv_b + TOK * 768;
    ushort_t* wb     = attn_b + TOKD;          // 655,360 elems (frag-ordered)
    uint_t*   bits   = (uint_t*)(wb + WQ_SZ + 7 * WS_SZ);

    ushort_t* wq_b  = wb;
    ushort_t* wfc_b = wb + WQ_SZ;
    ushort_t* wz_b  = wfc_b + WS_SZ;
    ushort_t* uz_b  = wz_b + WS_SZ;
    ushort_t* wr_b  = uz_b + WS_SZ;
    ushort_t* ur_b  = wr_b + WS_SZ;
    ushort_t* wg_b  = ur_b + WS_SZ;
    ushort_t* ug_b  = wg_b + WS_SZ;

    prep_kernel<<<NB_ADJ + NB_WC + NB_LN, 256, 0, stream>>>(
        adj, bits, w_qkv, w_fc, w_z, u_z, w_r, u_r, w_g, u_g, wb,
        x, ln_g, ln_b, xn_b);

    gemm_qkv<<<dim3(12, 128), 256, 0, stream>>>(xn_b, wq_b, b_qkv, qkv_b);

    attn_kernel<<<dim3(S_ / 64, B_ * H_), 256, 0, stream>>>(qkv_b, bits, attn_b);

    fused_gate<<<512, 256, 0, stream>>>(
        attn_b, x, wfc_b, wz_b, uz_b, wr_b, ur_b, wg_b, ug_b, b_fc, b_z, out);
}